// Round 2
// baseline (897.953 us; speedup 1.0000x reference)
//
#include <hip/hip_runtime.h>
#include <hip/hip_bf16.h>

#define NB 1024
#define DM 1024
#define DH 64
#define NH 16
#define NA 4
#define FEPS 1e-6f

// ---------------- K1: routing (logits, softmax, top-4, head lists) ----------------
__global__ __launch_bounds__(256) void k_route(
    const float* __restrict__ query,
    const float* __restrict__ We,
    const float* __restrict__ be,
    int* __restrict__ cnt,
    int* __restrict__ topi,
    float* __restrict__ topp,
    float* __restrict__ topl,
    int* __restrict__ slot,
    int* __restrict__ rows)
{
    int b = blockIdx.x, t = threadIdx.x;
    __shared__ float qs[DM];
    __shared__ float lg[NH];
    __shared__ int   sti[NA];
    __shared__ float stp[NA], stl[NA];
    ((float4*)qs)[t] = ((const float4*)(query + (size_t)b*DM))[t];
    __syncthreads();
    // 16 heads x 16 threads each
    int h = t >> 4, l = t & 15;
    const float* w = We + h*DM;
    float p = 0.f;
    for (int j = l; j < DM; j += 16) p += qs[j]*w[j];
    #pragma unroll
    for (int d = 8; d > 0; d >>= 1) p += __shfl_down(p, d, 16);
    if (l == 0) lg[h] = p + be[h];
    __syncthreads();
    if (t == 0) {
        float mx = lg[0];
        for (int i = 1; i < NH; i++) mx = fmaxf(mx, lg[i]);
        float s = 0.f, e[NH];
        for (int i = 0; i < NH; i++) { e[i] = expf(lg[i]-mx); s += e[i]; }
        float inv = 1.f/s;
        unsigned used = 0;
        for (int a = 0; a < NA; a++) {
            int bi = -1; float bv = -1e30f;
            for (int i = 0; i < NH; i++)
                if (!((used>>i)&1u) && lg[i] > bv) { bv = lg[i]; bi = i; }
            used |= 1u << bi;
            sti[a] = bi; stp[a] = e[bi]*inv; stl[a] = lg[bi];
        }
    }
    __syncthreads();
    if (t < NA) {
        int hh = sti[t];
        topi[b*NA+t] = hh; topp[b*NA+t] = stp[t]; topl[b*NA+t] = stl[t];
        int pos = atomicAdd(&cnt[hh], 1);
        rows[hh*NB + pos] = b*NA + t;   // code = b*4 + slot
    }
    if (t < NH) {
        int sl = -1;
        #pragma unroll
        for (int a = 0; a < NA; a++) if (sti[a] == t) sl = a;
        slot[b*NH + t] = sl;
    }
}

// ---------------- K2: gathered per-head projection GEMM (64 rows x 64 dims) -------
__global__ __launch_bounds__(256) void k_proj(
    const float* __restrict__ Xq, const float* __restrict__ Xk, const float* __restrict__ Xv,
    const float* __restrict__ Wq, const float* __restrict__ Wk, const float* __restrict__ Wv,
    const float* __restrict__ bq, const float* __restrict__ bk, const float* __restrict__ bv,
    const int* __restrict__ cnt, const int* __restrict__ rows,
    float* __restrict__ qb, float* __restrict__ kb, float* __restrict__ vb)
{
    int h = blockIdx.x, c = blockIdx.y, pz = blockIdx.z;
    int n = cnt[h];
    int r0 = c*64;
    if (r0 >= n) return;
    int nr = min(64, n - r0);
    const float* X    = pz==0 ? Xq : (pz==1 ? Xk : Xv);
    const float* W    = (pz==0 ? Wq : (pz==1 ? Wk : Wv)) + (size_t)h*DH*DM;
    const float* bias = (pz==0 ? bq : (pz==1 ? bk : bv)) + h*DH;
    float* outp = pz==0 ? qb : (pz==1 ? kb : vb);

    __shared__ float As[64*65];   // +1 pad breaks bank conflicts
    __shared__ float Bs[64*65];
    __shared__ int codes[64];
    int t = threadIdx.x;
    if (t < 64) codes[t] = rows[h*NB + r0 + min(t, nr-1)];
    __syncthreads();
    int tx = t & 15, ty = t >> 4;
    float acc[4][4] = {};
    int lr = t >> 2, k0 = (t & 3)*16;
    for (int kt = 0; kt < DM; kt += 64) {
        const float* srcA = X + (size_t)(codes[lr] >> 2)*DM + kt + k0;
        float* dA = As + lr*65 + k0;
        const float* srcB = W + (size_t)lr*DM + kt + k0;
        float* dB = Bs + lr*65 + k0;
        #pragma unroll
        for (int j = 0; j < 4; j++) {
            float4 fa = ((const float4*)srcA)[j];
            dA[j*4+0]=fa.x; dA[j*4+1]=fa.y; dA[j*4+2]=fa.z; dA[j*4+3]=fa.w;
            float4 fb = ((const float4*)srcB)[j];
            dB[j*4+0]=fb.x; dB[j*4+1]=fb.y; dB[j*4+2]=fb.z; dB[j*4+3]=fb.w;
        }
        __syncthreads();
        #pragma unroll 4
        for (int k = 0; k < 64; k++) {
            float a0[4], b0[4];
            #pragma unroll
            for (int i=0;i<4;i++) a0[i] = As[(ty*4+i)*65 + k];
            #pragma unroll
            for (int j=0;j<4;j++) b0[j] = Bs[(tx*4+j)*65 + k];
            #pragma unroll
            for (int i=0;i<4;i++)
                #pragma unroll
                for (int j=0;j<4;j++) acc[i][j] += a0[i]*b0[j];
        }
        __syncthreads();
    }
    #pragma unroll
    for (int i = 0; i < 4; i++) {
        int r = ty*4+i;
        if (r < nr) {
            int code = codes[r];
            #pragma unroll
            for (int j = 0; j < 4; j++)
                outp[code*DH + tx*4+j] = acc[i][j] + bias[tx*4+j];
        }
    }
}

// ---------------- K3: per-(b,h) state copy or linear-attention update -------------
__global__ __launch_bounds__(256) void k_update(
    const float* __restrict__ matrix,
    const float* __restrict__ normalizer,
    const float* __restrict__ Ww, const float* __restrict__ bw,
    const float* __restrict__ dlog,
    const int* __restrict__ slot, const float* __restrict__ topl,
    const float* __restrict__ qb, const float* __restrict__ kb,
    const float* __restrict__ vb, float* __restrict__ ob,
    float* __restrict__ om, float* __restrict__ on)
{
    int bh = blockIdx.x, t = threadIdx.x;
    const float* S = matrix + (size_t)bh*(DH*DH);
    float* So = om + (size_t)bh*(DH*DH);
    int sl = slot[bh];
    if (sl < 0) {
        // pure copy path (12/16 of all blocks): f32 -> f32
        #pragma unroll
        for (int j = 0; j < 4; j++) {
            int i4 = t + 256*j;
            ((float4*)So)[i4] = ((const float4*)S)[i4];
        }
        if (t < DH)
            on[(size_t)bh*DH + t] = normalizer[(size_t)bh*DH + t];
        return;
    }
    int b = bh >> 4, h = bh & 15;
    int code = b*NA + sl;
    __shared__ float st[DH*DH];
    __shared__ float pq[DH], pk[DH], vv[DH], qv[DH], Zs[DH];
    __shared__ float part[256];
    __shared__ float fd[DH], gd[DH];
    __shared__ float scal[4];
    if (t < DH) {
        float qq = qb[code*DH + t]; qv[t] = qq;
        float kk = kb[code*DH + t];
        pq[t] = qq > 0.f ? qq + 1.f : expf(qq);   // elu+1
        pk[t] = kk > 0.f ? kk + 1.f : expf(kk);
        vv[t] = vb[code*DH + t];
        Zs[t] = normalizer[(size_t)bh*DH + t];
    }
    #pragma unroll
    for (int j = 0; j < 4; j++)
        ((float4*)st)[t + 256*j] = ((const float4*)S)[t + 256*j];
    __syncthreads();
    // partial column sums of phi_q^T S : 4 d-groups x 64 columns
    {
        int e = t & 63, dg = t >> 6;
        float s = 0.f;
        #pragma unroll
        for (int d = 0; d < 16; d++) s += pq[dg*16 + d] * st[(dg*16+d)*DH + e];
        part[t] = s;
    }
    if (t < 64) {   // wave 0: scalar reductions
        float r1 = pq[t]*pk[t];            // phi_q . phi_k
        float r2 = pq[t]*(Zs[t]+pk[t]);    // phi_q . Z_new
        #pragma unroll
        for (int d = 32; d > 0; d >>= 1) {
            r1 += __shfl_down(r1, d, 64);
            r2 += __shfl_down(r2, d, 64);
        }
        if (t == 0) { scal[0] = r1; scal[1] = r2 + FEPS; }
    }
    __syncthreads();
    float pqk = scal[0], den = scal[1];
    if (t < 64) {
        float cs = part[t] + part[64+t] + part[128+t] + part[192+t];
        float o = (cs + pqk*vv[t]) / den;
        ob[code*DH + t] = o;
        float r3 = (o + qv[t]) * Ww[h*DH + t];
        #pragma unroll
        for (int d = 32; d > 0; d >>= 1) r3 += __shfl_down(r3, d, 64);
        if (t == 0) {
            float wl = topl[code] + r3 + bw[h];
            scal[2] = 1.f/(1.f + expf(-wl));   // wp
        }
    }
    __syncthreads();
    float wp = scal[2];
    if (t < 64) {
        float dec = 1.f/(1.f + expf(-dlog[h*DH + t]));
        float f1 = 1.f - wp*dec;
        fd[t] = f1;
        gd[t] = wp*pk[t];
        on[(size_t)bh*DH + t] = Zs[t]*f1 + wp*pk[t];
    }
    __syncthreads();
    #pragma unroll
    for (int j = 0; j < 4; j++) {
        int i4 = t + 256*j;
        int d = i4 >> 4, e0 = (i4 & 15)*4;   // 16 float4 per 64-wide row
        float4 f = ((const float4*)st)[i4];
        float F = fd[d], G = gd[d];
        float4 u = { f.x*F + G*vv[e0],   f.y*F + G*vv[e0+1],
                     f.z*F + G*vv[e0+2], f.w*F + G*vv[e0+3] };
        ((float4*)So)[i4] = u;
    }
}

// ---------------- K4: merged output projection per row ---------------------------
__global__ __launch_bounds__(256) void k_merge(
    const float* __restrict__ Wo, const float* __restrict__ bo,
    const int* __restrict__ topi, const float* __restrict__ topp,
    const float* __restrict__ ob, float* __restrict__ merged)
{
    int b = blockIdx.x, t = threadIdx.x;
    __shared__ float ov[NA*DH];
    __shared__ float tp[NA];
    __shared__ int   hh[NA];
    if (t < NA) { tp[t] = topp[b*NA+t]; hh[t] = topi[b*NA+t]; }
    __syncthreads();
    { int a = t >> 6; ov[t] = ob[(size_t)b*NA*DH + t] * tp[a]; }
    __syncthreads();
    float acc[4] = {0.f,0.f,0.f,0.f};   // m = t*4 + mm
    #pragma unroll
    for (int a = 0; a < NA; a++) {
        int h = hh[a];
        float tpa = tp[a];
        const float* wbase = Wo + (size_t)h*DM*DH;
        #pragma unroll
        for (int mm = 0; mm < 4; mm++) {
            int m = t*4 + mm;
            const float4* wr = (const float4*)(wbase + (size_t)m*DH);
            float s = 0.f;
            #pragma unroll
            for (int e4 = 0; e4 < 16; e4++) {
                float4 w = wr[e4];
                s += w.x*ov[a*DH+e4*4]   + w.y*ov[a*DH+e4*4+1]
                   + w.z*ov[a*DH+e4*4+2] + w.w*ov[a*DH+e4*4+3];
            }
            acc[mm] += s + tpa * bo[(size_t)h*DM + m];
        }
    }
    float4 u = { acc[0], acc[1], acc[2], acc[3] };
    ((float4*)merged)[b*256 + t] = u;
}

extern "C" void kernel_launch(void* const* d_in, const int* in_sizes, int n_in,
                              void* d_out, int out_size, void* d_ws, size_t ws_size,
                              hipStream_t stream)
{
    const float* query  = (const float*)d_in[0];
    const float* key    = (const float*)d_in[1];
    const float* value  = (const float*)d_in[2];
    const float* matrix = (const float*)d_in[3];
    const float* normal = (const float*)d_in[4];
    const float* Wq = (const float*)d_in[5];
    const float* bq = (const float*)d_in[6];
    const float* Wk = (const float*)d_in[7];
    const float* bk = (const float*)d_in[8];
    const float* Wv = (const float*)d_in[9];
    const float* bv = (const float*)d_in[10];
    const float* Wo = (const float*)d_in[11];
    const float* bo = (const float*)d_in[12];
    const float* We = (const float*)d_in[13];
    const float* be = (const float*)d_in[14];
    const float* Ww = (const float*)d_in[15];
    const float* bw = (const float*)d_in[16];
    const float* dlog = (const float*)d_in[17];

    float* ws = (float*)d_ws;
    int*   cnt  = (int*)ws;                  // 16 ints
    int*   topi = (int*)(ws + 16);           // 4096
    float* topp = ws + 16 + 4096;            // 4096
    float* topl = topp + 4096;               // 4096
    int*   slot = (int*)(topl + 4096);       // 16384
    int*   rows = slot + 16384;              // 16384
    float* qb = (float*)(rows + 16384);      // 262144
    float* kb = qb + 262144;
    float* vb = kb + 262144;
    float* ob = vb + 262144;

    float* out_merged = (float*)d_out;
    float* out_matrix = out_merged + (size_t)NB*DM;
    float* out_norm   = out_matrix + (size_t)NB*NH*DH*DH;

    hipMemsetAsync(cnt, 0, 16*sizeof(int), stream);
    k_route<<<NB, 256, 0, stream>>>(query, We, be, cnt, topi, topp, topl, slot, rows);
    k_proj<<<dim3(NH, NB/64, 3), 256, 0, stream>>>(query, key, value, Wq, Wk, Wv,
                                                   bq, bk, bv, cnt, rows, qb, kb, vb);
    k_update<<<NB*NH, 256, 0, stream>>>(matrix, normal, Ww, bw, dlog, slot, topl,
                                        qb, kb, vb, ob, out_matrix, out_norm);
    k_merge<<<NB, 256, 0, stream>>>(Wo, bo, topi, topp, ob, out_merged);
}